// Round 1
// baseline (4968.906 us; speedup 1.0000x reference)
//
#include <hip/hip_runtime.h>
#include <hip/hip_bf16.h>
#include <math.h>

#define VOCAB 32000
#define EMB   256
#define HID   512
#define BB    4
#define SS    512
#define G4H   2048   // 4*HID
#define BS    2048   // BB*SS
#define NWG   64

// workspace layout in floats
#define OFF_XP     0ull         // BS*G4H = 4194304
#define OFF_HSAVE  4194304ull   // BS*HID = 1048576
#define OFF_HBUF   5242880ull   // 2*BB*HID = 4096
#define OFF_SUMEXP 5246976ull   // BS = 2048
#define OFF_SYNC   5249024ull   // 2 uints (+slack)

// ---------------------------------------------------------------------------
// k1: xp[bs][g] = sum_e emb[batch[bs]][e] * w_ih[g][e] + b_ih[g] + b_hh[g]
// 64x64 tile, K=256, fp32
// ---------------------------------------------------------------------------
__global__ __launch_bounds__(256) void k_embed_xp(
    const int* __restrict__ batch, const float* __restrict__ emb,
    const float* __restrict__ w_ih, const float* __restrict__ b_ih,
    const float* __restrict__ b_hh, float* __restrict__ xp)
{
    __shared__ float Asl[16 * 64];
    __shared__ float Bsl[16 * 64];
    const int tid = threadIdx.x;
    const int bs0 = blockIdx.x * 64;
    const int g0  = blockIdx.y * 64;
    const int m  = tid & 63;
    const int kg = tid >> 6;      // 0..3
    const int tok = batch[bs0 + m];
    const float* arow = emb + (size_t)tok * EMB;
    const float* brow = w_ih + (size_t)(g0 + m) * EMB;
    const int tm = tid >> 4;      // 0..15
    const int tv = tid & 15;      // 0..15

    float acc[4][4] = {};
    for (int k0 = 0; k0 < EMB; k0 += 16) {
        float4 a4 = *(const float4*)(arow + k0 + kg * 4);
        float4 b4 = *(const float4*)(brow + k0 + kg * 4);
        __syncthreads();
        const int kb = kg * 4;
        Asl[(kb + 0) * 64 + m] = a4.x;
        Asl[(kb + 1) * 64 + m] = a4.y;
        Asl[(kb + 2) * 64 + m] = a4.z;
        Asl[(kb + 3) * 64 + m] = a4.w;
        Bsl[(kb + 0) * 64 + m] = b4.x;
        Bsl[(kb + 1) * 64 + m] = b4.y;
        Bsl[(kb + 2) * 64 + m] = b4.z;
        Bsl[(kb + 3) * 64 + m] = b4.w;
        __syncthreads();
#pragma unroll
        for (int k = 0; k < 16; ++k) {
            float4 av = *(const float4*)&Asl[k * 64 + tm * 4];
            float4 bv = *(const float4*)&Bsl[k * 64 + tv * 4];
            float a[4] = {av.x, av.y, av.z, av.w};
            float bb[4] = {bv.x, bv.y, bv.z, bv.w};
#pragma unroll
            for (int i = 0; i < 4; ++i)
#pragma unroll
                for (int j = 0; j < 4; ++j)
                    acc[i][j] += a[i] * bb[j];
        }
    }
    float bsum[4];
#pragma unroll
    for (int j = 0; j < 4; ++j) {
        int g = g0 + tv * 4 + j;
        bsum[j] = b_ih[g] + b_hh[g];
    }
#pragma unroll
    for (int i = 0; i < 4; ++i) {
        int row = bs0 + tm * 4 + i;
        float4 o;
        o.x = acc[i][0] + bsum[0];
        o.y = acc[i][1] + bsum[1];
        o.z = acc[i][2] + bsum[2];
        o.w = acc[i][3] + bsum[3];
        *(float4*)(xp + (size_t)row * G4H + g0 + tv * 4) = o;
    }
}

// ---------------------------------------------------------------------------
// k2: persistent LSTM. 64 WGs x 512 threads. WG bw owns hidden units
// [bw*8, bw*8+8) for all 4 chains (32 gate rows), w_hh slice as bf16 in LDS.
// ---------------------------------------------------------------------------
__global__ __launch_bounds__(512) void k_lstm(
    const float* __restrict__ w_hh, const float* __restrict__ xp,
    float* __restrict__ hbuf, float* __restrict__ hsave,
    unsigned* __restrict__ sync)
{
    __shared__ unsigned short wl[32 * 514];  // padded stride: banks (r+kp)%32
    __shared__ float hl[4 * 516];            // padded stride
    __shared__ float gtmp[512];
    __shared__ float gacc[128];
    __shared__ float xs[128];

    const int tid = threadIdx.x;
    const int bw  = blockIdx.x;

    // preload w_hh slice as bf16 (RNE)
    for (int idx = tid; idx < 32 * 512; idx += 512) {
        int r = idx >> 9, k = idx & 511;
        int gr = (r >> 3) * HID + bw * 8 + (r & 7);
        unsigned u = __float_as_uint(w_hh[(size_t)gr * HID + k]);
        u += 0x7fffu + ((u >> 16) & 1u);
        wl[r * 514 + k] = (unsigned short)(u >> 16);
    }

    const int task = tid & 127;   // c*32 + r
    const int q    = tid >> 7;    // 0..3 (k-quarter)
    const int c    = task >> 5;   // chain
    const int r    = task & 31;   // gate row within slice (g*8 + jl)

    float cst = 0.f;              // cell state (threads tid<32)
    unsigned target = 0;
    unsigned* cnt   = sync;
    unsigned* epoch = sync + 1;
    bool broken = false;

    for (int t = 0; t < SS; ++t) {
        const int p = t & 1;
        // load h (all 4 chains) into LDS
        {
            int i4 = tid * 4;
            int hc = i4 >> 9, hk = i4 & 511;
            float4 h4 = *(const float4*)(hbuf + p * (BB * HID) + hc * HID + hk);
            hl[hc * 516 + hk + 0] = h4.x;
            hl[hc * 516 + hk + 1] = h4.y;
            hl[hc * 516 + hk + 2] = h4.z;
            hl[hc * 516 + hk + 3] = h4.w;
        }
        if (tid < 128) {
            int cc = tid >> 5, rr = tid & 31;
            int col = (rr >> 3) * HID + bw * 8 + (rr & 7);
            xs[tid] = xp[(size_t)(cc * SS + t) * G4H + col];
        }
        __syncthreads();

        // partial dot: 128 elements of h[c] . w_hh_row[r]
        float acc = 0.f;
        {
            const unsigned short* wrow = &wl[r * 514 + q * 128];
            const float* hrow = &hl[c * 516 + q * 128];
#pragma unroll 8
            for (int kp = 0; kp < 64; ++kp) {
                unsigned wp = *(const unsigned*)(wrow + kp * 2);
                float2 h2 = *(const float2*)(hrow + kp * 2);
                float w0 = __uint_as_float(wp << 16);
                float w1 = __uint_as_float(wp & 0xffff0000u);
                acc += h2.x * w0 + h2.y * w1;
            }
        }
        gtmp[tid] = acc;
        __syncthreads();
        if (tid < 128) {
            gacc[tid] = gtmp[tid] + gtmp[tid + 128] + gtmp[tid + 256] +
                        gtmp[tid + 384] + xs[tid];
        }
        __syncthreads();
        if (tid < 32) {
            int ch = tid >> 3, jl = tid & 7;
            float iv = gacc[ch * 32 + jl];
            float fv = gacc[ch * 32 + 8 + jl];
            float gv = gacc[ch * 32 + 16 + jl];
            float ov = gacc[ch * 32 + 24 + jl];
            float si = 1.f / (1.f + __expf(-iv));
            float sf = 1.f / (1.f + __expf(-fv));
            float so = 1.f / (1.f + __expf(-ov));
            cst = sf * cst + si * tanhf(gv);
            float hv = so * tanhf(cst);
            int jg = bw * 8 + jl;
            hbuf[(p ^ 1) * (BB * HID) + ch * HID + jg] = hv;
            hsave[((size_t)(ch * SS + t)) * HID + jg] = hv;
        }
        __syncthreads();

        // inter-WG barrier (epoch-counting, agent scope)
        target++;
        if (tid == 0) {
            __threadfence();   // flush WG stores (L2 -> coherence point)
            if (!broken) {
                unsigned old = __hip_atomic_fetch_add(cnt, 1u, __ATOMIC_RELAXED,
                                                      __HIP_MEMORY_SCOPE_AGENT);
                if (old == NWG - 1) {
                    __hip_atomic_store(cnt, 0u, __ATOMIC_RELAXED,
                                       __HIP_MEMORY_SCOPE_AGENT);
                    __hip_atomic_fetch_add(epoch, 1u, __ATOMIC_RELEASE,
                                           __HIP_MEMORY_SCOPE_AGENT);
                } else {
                    int guard = 0;
                    while (__hip_atomic_load(epoch, __ATOMIC_ACQUIRE,
                                             __HIP_MEMORY_SCOPE_AGENT) < target) {
                        __builtin_amdgcn_s_sleep(2);
                        if (++guard > 4000000) { broken = true; break; }
                    }
                }
            }
            __threadfence();   // invalidate for fresh reads next step
        }
        __syncthreads();
    }
}

// ---------------------------------------------------------------------------
// k3: logits tile (64 bs x 64 v, K=512) + bias, exp, partial row-sums ->
// atomicAdd into sumexp[bs]
// ---------------------------------------------------------------------------
__global__ __launch_bounds__(256) void k_logits_lse(
    const float* __restrict__ hsave, const float* __restrict__ Wm,
    const float* __restrict__ bias, float* __restrict__ sumexp)
{
    __shared__ float Asl[16 * 64];
    __shared__ float Bsl[16 * 64];
    const int tid = threadIdx.x;
    const int bs0 = blockIdx.x * 64;
    const int v0  = blockIdx.y * 64;
    const int m  = tid & 63;
    const int kg = tid >> 6;
    const float* arow = hsave + (size_t)(bs0 + m) * HID;
    const float* brow = Wm + (size_t)(v0 + m) * HID;
    const int tm = tid >> 4;
    const int tv = tid & 15;

    float acc[4][4] = {};
    for (int k0 = 0; k0 < HID; k0 += 16) {
        float4 a4 = *(const float4*)(arow + k0 + kg * 4);
        float4 b4 = *(const float4*)(brow + k0 + kg * 4);
        __syncthreads();
        const int kb = kg * 4;
        Asl[(kb + 0) * 64 + m] = a4.x;
        Asl[(kb + 1) * 64 + m] = a4.y;
        Asl[(kb + 2) * 64 + m] = a4.z;
        Asl[(kb + 3) * 64 + m] = a4.w;
        Bsl[(kb + 0) * 64 + m] = b4.x;
        Bsl[(kb + 1) * 64 + m] = b4.y;
        Bsl[(kb + 2) * 64 + m] = b4.z;
        Bsl[(kb + 3) * 64 + m] = b4.w;
        __syncthreads();
#pragma unroll
        for (int k = 0; k < 16; ++k) {
            float4 av = *(const float4*)&Asl[k * 64 + tm * 4];
            float4 bv = *(const float4*)&Bsl[k * 64 + tv * 4];
            float a[4] = {av.x, av.y, av.z, av.w};
            float bb[4] = {bv.x, bv.y, bv.z, bv.w};
#pragma unroll
            for (int i = 0; i < 4; ++i)
#pragma unroll
                for (int j = 0; j < 4; ++j)
                    acc[i][j] += a[i] * bb[j];
        }
    }
    float rsum[4] = {0.f, 0.f, 0.f, 0.f};
#pragma unroll
    for (int j = 0; j < 4; ++j) {
        float bj = bias[v0 + tv * 4 + j];
#pragma unroll
        for (int i = 0; i < 4; ++i)
            rsum[i] += __expf(acc[i][j] + bj);
    }
#pragma unroll
    for (int i = 0; i < 4; ++i) {
        float s = rsum[i];
        s += __shfl_down(s, 8, 16);
        s += __shfl_down(s, 4, 16);
        s += __shfl_down(s, 2, 16);
        s += __shfl_down(s, 1, 16);
        if (tv == 0) atomicAdd(&sumexp[bs0 + tm * 4 + i], s);
    }
}

// ---------------------------------------------------------------------------
// k4: decode the contiguous-view gather, recompute 2048 picked logits,
// subtract lse, accumulate -mean into out.
// ---------------------------------------------------------------------------
__global__ __launch_bounds__(256) void k_final(
    const int* __restrict__ batch, const float* __restrict__ hsave,
    const float* __restrict__ Wm, const float* __restrict__ bias,
    const float* __restrict__ sumexp, float* __restrict__ out)
{
    const int i = blockIdx.x * 256 + threadIdx.x;
    if (i >= BS) return;
    const unsigned tgt = (unsigned)batch[i];     // flat [B,S] == flat [S,B] view
    const unsigned s2 = i >> 2, b2 = i & 3;
    const unsigned j = s2 * (VOCAB * BB) + tgt * BB + b2;
    const unsigned SV = (unsigned)SS * VOCAB;    // 16384000
    const unsigned b_o = j / SV;
    const unsigned rr = j - b_o * SV;
    const unsigned s_o = rr / VOCAB;
    const unsigned v_o = rr - s_o * VOCAB;
    const unsigned row = b_o * SS + s_o;
    const float* hp = hsave + (size_t)row * HID;
    const float* wp = Wm + (size_t)v_o * HID;
    float d = bias[v_o];
    for (int k = 0; k < HID; ++k) d += hp[k] * wp[k];
    float picked = d - logf(sumexp[row]);
    atomicAdd(out, -picked * (1.f / (float)BS));
}

// ---------------------------------------------------------------------------
extern "C" void kernel_launch(void* const* d_in, const int* in_sizes, int n_in,
                              void* d_out, int out_size, void* d_ws, size_t ws_size,
                              hipStream_t stream)
{
    const int*   batch = (const int*)d_in[0];
    const float* emb   = (const float*)d_in[1];
    const float* w_ih  = (const float*)d_in[2];
    const float* w_hh  = (const float*)d_in[3];
    const float* b_ih  = (const float*)d_in[4];
    const float* b_hh  = (const float*)d_in[5];
    const float* Wm    = (const float*)d_in[6];
    const float* bvec  = (const float*)d_in[7];
    float* out = (float*)d_out;
    float* ws  = (float*)d_ws;

    float* xp      = ws + OFF_XP;
    float* hsave   = ws + OFF_HSAVE;
    float* hbuf    = ws + OFF_HBUF;
    float* sumexp  = ws + OFF_SUMEXP;
    unsigned* sync = (unsigned*)(ws + OFF_SYNC);

    // zero hbuf + sumexp + sync (contiguous) and out, every launch
    hipMemsetAsync(hbuf, 0, (4096 + 2048 + 16) * sizeof(float), stream);
    hipMemsetAsync(out, 0, sizeof(float), stream);

    dim3 g1(BS / 64, G4H / 64);
    k_embed_xp<<<g1, 256, 0, stream>>>(batch, emb, w_ih, b_ih, b_hh, xp);

    k_lstm<<<NWG, 512, 0, stream>>>(w_hh, xp, hbuf, hsave, sync);

    dim3 g3(BS / 64, VOCAB / 64);
    k_logits_lse<<<g3, 256, 0, stream>>>(hsave, Wm, bvec, sumexp);

    k_final<<<BS / 256, 256, 0, stream>>>(batch, hsave, Wm, bvec, sumexp, out);
}

// Round 2
// 1664.831 us; speedup vs baseline: 2.9846x; 2.9846x over previous
//
#include <hip/hip_runtime.h>
#include <hip/hip_bf16.h>
#include <math.h>

#define VOCAB 32000
#define EMB   256
#define HID   512
#define BB    4
#define SS    512
#define G4H   2048   // 4*HID
#define BS    2048   // BB*SS

typedef unsigned int   u32;
typedef unsigned short u16;
using short8 = __attribute__((ext_vector_type(8))) short;
using f32x4  = __attribute__((ext_vector_type(4))) float;

// workspace layout (float units).  Region [0, 8192000) is time-shared:
//   xp (4194304 floats) lives from k1 until k2 completes,
//   then WB (32000*512 bf16 = 8192000 float-slots) overwrites it (wcvt runs after k2).
#define OFF_HSB  8192000ull   // hsaveB: 2048*512 bf16 = 524288 float-slots
#define OFF_HG   8716288ull   // hG: 2*4*512 floats
#define OFF_FLG  8720384ull   // flags: 64 * 32 u32 (one per 128B line)
#define OFF_SUM  8722432ull   // sumexp: 2048 floats
// end = 8724480 floats = 34.9 MB

__device__ inline unsigned packbf(float a, float b) {
    unsigned ua = __float_as_uint(a), ub = __float_as_uint(b);
    ua += 0x7fffu + ((ua >> 16) & 1u);
    ub += 0x7fffu + ((ub >> 16) & 1u);
    return (ua >> 16) | (ub & 0xffff0000u);
}

#define GLOAD_LDS16(gp, lp) __builtin_amdgcn_global_load_lds( \
    (const __attribute__((address_space(1))) void*)(gp),      \
    (__attribute__((address_space(3))) void*)(lp), 16, 0, 0)

// ---------------------------------------------------------------------------
// k1: xp[bs][g] = sum_e emb[batch[bs]][e] * w_ih[g][e] + b_ih[g] + b_hh[g]
// ---------------------------------------------------------------------------
__global__ __launch_bounds__(256) void k_embed_xp(
    const int* __restrict__ batch, const float* __restrict__ emb,
    const float* __restrict__ w_ih, const float* __restrict__ b_ih,
    const float* __restrict__ b_hh, float* __restrict__ xp)
{
    __shared__ float Asl[16 * 64];
    __shared__ float Bsl[16 * 64];
    const int tid = threadIdx.x;
    const int bs0 = blockIdx.x * 64;
    const int g0  = blockIdx.y * 64;
    const int m  = tid & 63;
    const int kg = tid >> 6;
    const int tok = batch[bs0 + m];
    const float* arow = emb + (size_t)tok * EMB;
    const float* brow = w_ih + (size_t)(g0 + m) * EMB;
    const int tm = tid >> 4;
    const int tv = tid & 15;

    float acc[4][4] = {};
    for (int k0 = 0; k0 < EMB; k0 += 16) {
        float4 a4 = *(const float4*)(arow + k0 + kg * 4);
        float4 b4 = *(const float4*)(brow + k0 + kg * 4);
        __syncthreads();
        const int kb = kg * 4;
        Asl[(kb + 0) * 64 + m] = a4.x;
        Asl[(kb + 1) * 64 + m] = a4.y;
        Asl[(kb + 2) * 64 + m] = a4.z;
        Asl[(kb + 3) * 64 + m] = a4.w;
        Bsl[(kb + 0) * 64 + m] = b4.x;
        Bsl[(kb + 1) * 64 + m] = b4.y;
        Bsl[(kb + 2) * 64 + m] = b4.z;
        Bsl[(kb + 3) * 64 + m] = b4.w;
        __syncthreads();
#pragma unroll
        for (int k = 0; k < 16; ++k) {
            float4 av = *(const float4*)&Asl[k * 64 + tm * 4];
            float4 bv = *(const float4*)&Bsl[k * 64 + tv * 4];
            float a[4] = {av.x, av.y, av.z, av.w};
            float bb[4] = {bv.x, bv.y, bv.z, bv.w};
#pragma unroll
            for (int i = 0; i < 4; ++i)
#pragma unroll
                for (int j = 0; j < 4; ++j)
                    acc[i][j] += a[i] * bb[j];
        }
    }
    float bsum[4];
#pragma unroll
    for (int j = 0; j < 4; ++j) {
        int g = g0 + tv * 4 + j;
        bsum[j] = b_ih[g] + b_hh[g];
    }
#pragma unroll
    for (int i = 0; i < 4; ++i) {
        int row = bs0 + tm * 4 + i;
        float4 o;
        o.x = acc[i][0] + bsum[0];
        o.y = acc[i][1] + bsum[1];
        o.z = acc[i][2] + bsum[2];
        o.w = acc[i][3] + bsum[3];
        *(float4*)(xp + (size_t)row * G4H + g0 + tv * 4) = o;
    }
}

// ---------------------------------------------------------------------------
// k2: persistent LSTM, chain-local flag sync.
// 64 WGs x 512 thr: WG = chain (wg>>4) x slice (wg&15); slice owns 32 hidden
// units -> 128 gate rows. w_hh rows live in registers (packed bf16).
// h exchanged via relaxed-agent atomics (IF$ = coherence point), per-WG
// monotonic step flags on private cachelines (no RMW contention).
// ---------------------------------------------------------------------------
__global__ __launch_bounds__(512) void k_lstm(
    const float* __restrict__ w_hh, const float* __restrict__ xp,
    float* __restrict__ hG, u32* __restrict__ flags,
    u16* __restrict__ hsaveB)
{
    __shared__ float hl[512];
    __shared__ float gtmp[512];
    __shared__ float gacc[128];
    __shared__ float xs[128];

    const int tid   = threadIdx.x;
    const int wg    = blockIdx.x;
    const int c     = wg >> 4;        // chain 0..3
    const int slice = wg & 15;
    const int j0    = slice * 32;
    const int r     = tid & 127;      // gate row in slice
    const int q     = tid >> 7;       // k-quarter 0..3
    const int g     = r >> 5;         // gate 0..3 (i,f,g,o)
    const int jl    = r & 31;         // hidden unit within slice
    const int grow  = g * HID + j0 + jl;

    // preload this thread's 128 w_hh values as packed bf16 (64 VGPRs)
    unsigned wreg[64];
    {
        const float* wsrc = w_hh + (size_t)grow * HID + q * 128;
#pragma unroll
        for (int i = 0; i < 32; ++i) {
            float4 f = *(const float4*)(wsrc + i * 4);
            wreg[2 * i]     = packbf(f.x, f.y);
            wreg[2 * i + 1] = packbf(f.z, f.w);
        }
    }

    u32* myflags = flags + c * 16 * 32;  // this chain's 16 flags, stride 32 u32
    float cst = 0.f;

    for (int t = 0; t < SS; ++t) {
        const int p = t & 1;
        // xp for this step (independent of h) - load early
        if (tid < 128)
            xs[tid] = xp[(size_t)(c * SS + t) * G4H +
                         (tid >> 5) * HID + j0 + (tid & 31)];
        // wait for h(t): all 16 slices of this chain done with step t-1
        if (tid < 16) {
            u32* f = myflags + tid * 32;
            int guard = 0;
            while (__hip_atomic_load(f, __ATOMIC_RELAXED,
                                     __HIP_MEMORY_SCOPE_AGENT) < (u32)t) {
                __builtin_amdgcn_s_sleep(1);
                if (++guard > 10000000) break;
            }
        }
        __syncthreads();
        // fresh h(t) from coherence point
        hl[tid] = __hip_atomic_load(hG + p * (BB * HID) + c * HID + tid,
                                    __ATOMIC_RELAXED, __HIP_MEMORY_SCOPE_AGENT);
        __syncthreads();

        // 128-element partial dot: row r, quarter q
        float acc = 0.f;
        {
            const float2* hq = (const float2*)(hl + q * 128);
#pragma unroll
            for (int kp = 0; kp < 64; ++kp) {
                unsigned w2 = wreg[kp];
                float2 h2 = hq[kp];
                acc = fmaf(h2.x, __uint_as_float(w2 << 16), acc);
                acc = fmaf(h2.y, __uint_as_float(w2 & 0xffff0000u), acc);
            }
        }
        gtmp[tid] = acc;
        __syncthreads();
        if (tid < 128)
            gacc[tid] = gtmp[tid] + gtmp[tid + 128] + gtmp[tid + 256] +
                        gtmp[tid + 384] + xs[tid];
        __syncthreads();
        if (tid < 32) {
            float iv = gacc[tid],      fv = gacc[32 + tid];
            float gv = gacc[64 + tid], ov = gacc[96 + tid];
            float si = 1.f / (1.f + __expf(-iv));
            float sf = 1.f / (1.f + __expf(-fv));
            float so = 1.f / (1.f + __expf(-ov));
            cst = sf * cst + si * tanhf(gv);
            float hv = so * tanhf(cst);
            __hip_atomic_store(hG + (p ^ 1) * (BB * HID) + c * HID + j0 + tid,
                               hv, __ATOMIC_RELAXED, __HIP_MEMORY_SCOPE_AGENT);
            unsigned u = __float_as_uint(hv);
            u += 0x7fffu + ((u >> 16) & 1u);
            hsaveB[(size_t)(c * SS + t) * HID + j0 + tid] = (u16)(u >> 16);
        }
        // release: all 32 h-stores are in wave 0; drain them, then set flag
        if (tid < 64) {
            asm volatile("s_waitcnt vmcnt(0)" ::: "memory");
            if (tid == 0)
                __hip_atomic_store(myflags + slice * 32, (u32)(t + 1),
                                   __ATOMIC_RELAXED, __HIP_MEMORY_SCOPE_AGENT);
        }
    }
}

// ---------------------------------------------------------------------------
// wcvt: W fp32 -> bf16 (RNE), 16.384M elems
// ---------------------------------------------------------------------------
__global__ __launch_bounds__(256) void k_wcvt(
    const float* __restrict__ W, u16* __restrict__ WB)
{
    int i = blockIdx.x * 256 + threadIdx.x;   // < 4,096,000 float4 groups
    float4 f = ((const float4*)W)[i];
    uint2 o;
    o.x = packbf(f.x, f.y);
    o.y = packbf(f.z, f.w);
    ((uint2*)WB)[i] = o;
}

// ---------------------------------------------------------------------------
// k3: bf16 MFMA logits + fused exp/row-sum -> sumexp.
// 128x128 tile, BK=64, global_load_lds(16B) with chunk-XOR swizzle
// (pre-swizzled source, swizzled ds_read -> ~2-way conflicts instead of 16).
// ---------------------------------------------------------------------------
__global__ __launch_bounds__(256) void k_logits_lse(
    const u16* __restrict__ hsaveB, const u16* __restrict__ WB,
    const float* __restrict__ bias, float* __restrict__ sumexp)
{
    __shared__ u16 As[128 * 64];
    __shared__ u16 Bs[128 * 64];
    const int tid  = threadIdx.x;
    const int lane = tid & 63;
    const int wave = tid >> 6;       // 0..3
    const int wr   = wave >> 1;      // row quadrant
    const int wc   = wave & 1;       // col quadrant
    const int bs0  = blockIdx.x * 128;
    const int v0   = blockIdx.y * 128;
    const int lr   = lane & 15;
    const int lc   = lane >> 4;

    f32x4 acc[4][4];
#pragma unroll
    for (int m = 0; m < 4; ++m)
#pragma unroll
        for (int n = 0; n < 4; ++n)
            acc[m][n] = (f32x4){0.f, 0.f, 0.f, 0.f};

    for (int k0 = 0; k0 < HID; k0 += 64) {
        // stage A and B tiles: [128 rows][64 cols] bf16, 16B chunks,
        // source pre-swizzled: LDS chunk (row,cl) holds global chunk cl^(row&7)
#pragma unroll
        for (int it = 0; it < 4; ++it) {
            int base = it * 256 + wave * 64;
            int idx  = base + lane;
            int row  = idx >> 3, cl = idx & 7;
            int gcl  = cl ^ (row & 7);
            const u16* gA = hsaveB + (size_t)(bs0 + row) * HID + k0 + gcl * 8;
            GLOAD_LDS16(gA, As + (size_t)base * 8);
            const u16* gB = WB + (size_t)(v0 + row) * HID + k0 + gcl * 8;
            GLOAD_LDS16(gB, Bs + (size_t)base * 8);
        }
        asm volatile("s_waitcnt vmcnt(0)" ::: "memory");
        __syncthreads();

        short8 af[4][2], bf[4][2];
#pragma unroll
        for (int m = 0; m < 4; ++m)
#pragma unroll
            for (int ks = 0; ks < 2; ++ks) {
                int rowA = wr * 64 + m * 16 + lr;
                int swa  = ((ks * 4 + lc) ^ (rowA & 7)) * 8;
                af[m][ks] = *(const short8*)&As[rowA * 64 + swa];
                int rowB = wc * 64 + m * 16 + lr;
                int swb  = ((ks * 4 + lc) ^ (rowB & 7)) * 8;
                bf[m][ks] = *(const short8*)&Bs[rowB * 64 + swb];
            }
#pragma unroll
        for (int m = 0; m < 4; ++m)
#pragma unroll
            for (int n = 0; n < 4; ++n)
#pragma unroll
                for (int ks = 0; ks < 2; ++ks)
                    acc[m][n] = __builtin_amdgcn_mfma_f32_16x16x32_bf16(
                        af[m][ks], bf[n][ks], acc[m][n], 0, 0, 0);
        __syncthreads();
    }

    // epilogue: exp(logit + bias), reduce across the 128 cols of this tile
    float bn[4];
#pragma unroll
    for (int n = 0; n < 4; ++n)
        bn[n] = bias[v0 + wc * 64 + n * 16 + lr];

#pragma unroll
    for (int m = 0; m < 4; ++m) {
        float p0 = 0.f, p1 = 0.f, p2 = 0.f, p3 = 0.f;
#pragma unroll
        for (int n = 0; n < 4; ++n) {
            float b = bn[n];
            p0 += __expf(acc[m][n][0] + b);
            p1 += __expf(acc[m][n][1] + b);
            p2 += __expf(acc[m][n][2] + b);
            p3 += __expf(acc[m][n][3] + b);
        }
#pragma unroll
        for (int off = 1; off < 16; off <<= 1) {
            p0 += __shfl_xor(p0, off);
            p1 += __shfl_xor(p1, off);
            p2 += __shfl_xor(p2, off);
            p3 += __shfl_xor(p3, off);
        }
        if (lr == 0) {
            int row = bs0 + wr * 64 + m * 16 + lc * 4;
            atomicAdd(&sumexp[row + 0], p0);
            atomicAdd(&sumexp[row + 1], p1);
            atomicAdd(&sumexp[row + 2], p2);
            atomicAdd(&sumexp[row + 3], p3);
        }
    }
}

// ---------------------------------------------------------------------------
// k4: one wave per (b,s): decode contiguous-view gather, recompute picked
// logit (bf16), subtract log(sumexp), accumulate -mean.
// ---------------------------------------------------------------------------
__device__ inline float dotp(u32 h, u32 w) {
    return __uint_as_float(h << 16) * __uint_as_float(w << 16) +
           __uint_as_float(h & 0xffff0000u) * __uint_as_float(w & 0xffff0000u);
}

__global__ __launch_bounds__(256) void k_final(
    const int* __restrict__ batch, const u16* __restrict__ hsaveB,
    const u16* __restrict__ WB, const float* __restrict__ bias,
    const float* __restrict__ sumexp, float* __restrict__ out)
{
    const int gt   = blockIdx.x * 256 + threadIdx.x;
    const int wid  = gt >> 6;      // 0..2047
    const int lane = gt & 63;
    const unsigned tgt = (unsigned)batch[wid];
    const unsigned s2 = wid >> 2, b2 = wid & 3;
    const unsigned j = s2 * (VOCAB * BB) + tgt * BB + b2;
    const unsigned SV = (unsigned)SS * VOCAB;
    const unsigned b_o = j / SV;
    const unsigned rr = j - b_o * SV;
    const unsigned s_o = rr / VOCAB;
    const unsigned v_o = rr - s_o * VOCAB;
    const unsigned row = b_o * SS + s_o;

    uint4 hu = *(const uint4*)(hsaveB + (size_t)row * HID + lane * 8);
    uint4 wu = *(const uint4*)(WB + (size_t)v_o * HID + lane * 8);
    float d = dotp(hu.x, wu.x) + dotp(hu.y, wu.y) +
              dotp(hu.z, wu.z) + dotp(hu.w, wu.w);
#pragma unroll
    for (int off = 32; off >= 1; off >>= 1)
        d += __shfl_xor(d, off);
    if (lane == 0) {
        float picked = d + bias[v_o] - logf(sumexp[row]);
        atomicAdd(out, -picked * (1.f / (float)BS));
    }
}

// ---------------------------------------------------------------------------
extern "C" void kernel_launch(void* const* d_in, const int* in_sizes, int n_in,
                              void* d_out, int out_size, void* d_ws, size_t ws_size,
                              hipStream_t stream)
{
    const int*   batch = (const int*)d_in[0];
    const float* emb   = (const float*)d_in[1];
    const float* w_ih  = (const float*)d_in[2];
    const float* w_hh  = (const float*)d_in[3];
    const float* b_ih  = (const float*)d_in[4];
    const float* b_hh  = (const float*)d_in[5];
    const float* Wm    = (const float*)d_in[6];
    const float* bvec  = (const float*)d_in[7];
    float* out = (float*)d_out;
    float* ws  = (float*)d_ws;

    float* xp      = ws;                       // dead after k2
    u16*   WB      = (u16*)ws;                 // written after k2 (time-shared)
    u16*   hsaveB  = (u16*)(ws + OFF_HSB);
    float* hG      = ws + OFF_HG;
    u32*   flags   = (u32*)(ws + OFF_FLG);
    float* sumexp  = ws + OFF_SUM;

    // zero hG + flags + sumexp (contiguous) and out
    hipMemsetAsync(hG, 0, (4096 + 2048 + 2048) * sizeof(float), stream);
    hipMemsetAsync(out, 0, sizeof(float), stream);

    dim3 g1(BS / 64, G4H / 64);
    k_embed_xp<<<g1, 256, 0, stream>>>(batch, emb, w_ih, b_ih, b_hh, xp);

    k_lstm<<<64, 512, 0, stream>>>(w_hh, xp, hG, flags, hsaveB);

    k_wcvt<<<VOCAB * HID / 4 / 256, 256, 0, stream>>>(Wm, WB);

    dim3 g3(BS / 128, VOCAB / 128);
    k_logits_lse<<<g3, 256, 0, stream>>>(hsaveB, WB, bvec, sumexp);

    k_final<<<BS * 64 / 256, 256, 0, stream>>>(batch, hsaveB, WB, bvec, sumexp, out);
}

// Round 3
// 1141.593 us; speedup vs baseline: 4.3526x; 1.4583x over previous
//
#include <hip/hip_runtime.h>
#include <hip/hip_bf16.h>
#include <math.h>

#define VOCAB 32000
#define EMB   256
#define HID   512
#define BB    4
#define SS    512
#define G4H   2048   // 4*HID
#define BS    2048   // BB*SS

typedef unsigned int   u32;
typedef unsigned short u16;
using short8 = __attribute__((ext_vector_type(8))) short;
using f32x4  = __attribute__((ext_vector_type(4))) float;

// workspace layout (float units).  Region [0, 8192000) is time-shared:
//   xp (4194304 floats) lives from k1 until k2 completes,
//   then WB (32000*512 bf16 = 8192000 float-slots) overwrites it.
#define OFF_HSB  8192000ull   // hsaveB: 2048*512 bf16 = 524288 float-slots
#define OFF_HW   8716288ull   // hw: 2*4*512 u32 tagged h words = 4096 slots
#define OFF_FLG  8720384ull   // (unused, kept for contiguous memset)
#define OFF_SUM  8722432ull   // sumexp: 2048 floats
// end = 8724480 floats = 34.9 MB

__device__ inline unsigned packbf(float a, float b) {
    unsigned ua = __float_as_uint(a), ub = __float_as_uint(b);
    ua += 0x7fffu + ((ua >> 16) & 1u);
    ub += 0x7fffu + ((ub >> 16) & 1u);
    return (ua >> 16) | (ub & 0xffff0000u);
}

#define GLOAD_LDS16(gp, lp) __builtin_amdgcn_global_load_lds( \
    (const __attribute__((address_space(1))) void*)(gp),      \
    (__attribute__((address_space(3))) void*)(lp), 16, 0, 0)

// ---------------------------------------------------------------------------
// k1: xp[bs][g] = sum_e emb[batch[bs]][e] * w_ih[g][e] + b_ih[g] + b_hh[g]
// ---------------------------------------------------------------------------
__global__ __launch_bounds__(256) void k_embed_xp(
    const int* __restrict__ batch, const float* __restrict__ emb,
    const float* __restrict__ w_ih, const float* __restrict__ b_ih,
    const float* __restrict__ b_hh, float* __restrict__ xp)
{
    __shared__ float Asl[16 * 64];
    __shared__ float Bsl[16 * 64];
    const int tid = threadIdx.x;
    const int bs0 = blockIdx.x * 64;
    const int g0  = blockIdx.y * 64;
    const int m  = tid & 63;
    const int kg = tid >> 6;
    const int tok = batch[bs0 + m];
    const float* arow = emb + (size_t)tok * EMB;
    const float* brow = w_ih + (size_t)(g0 + m) * EMB;
    const int tm = tid >> 4;
    const int tv = tid & 15;

    float acc[4][4] = {};
    for (int k0 = 0; k0 < EMB; k0 += 16) {
        float4 a4 = *(const float4*)(arow + k0 + kg * 4);
        float4 b4 = *(const float4*)(brow + k0 + kg * 4);
        __syncthreads();
        const int kb = kg * 4;
        Asl[(kb + 0) * 64 + m] = a4.x;
        Asl[(kb + 1) * 64 + m] = a4.y;
        Asl[(kb + 2) * 64 + m] = a4.z;
        Asl[(kb + 3) * 64 + m] = a4.w;
        Bsl[(kb + 0) * 64 + m] = b4.x;
        Bsl[(kb + 1) * 64 + m] = b4.y;
        Bsl[(kb + 2) * 64 + m] = b4.z;
        Bsl[(kb + 3) * 64 + m] = b4.w;
        __syncthreads();
#pragma unroll
        for (int k = 0; k < 16; ++k) {
            float4 av = *(const float4*)&Asl[k * 64 + tm * 4];
            float4 bv = *(const float4*)&Bsl[k * 64 + tv * 4];
            float a[4] = {av.x, av.y, av.z, av.w};
            float bb[4] = {bv.x, bv.y, bv.z, bv.w};
#pragma unroll
            for (int i = 0; i < 4; ++i)
#pragma unroll
                for (int j = 0; j < 4; ++j)
                    acc[i][j] += a[i] * bb[j];
        }
    }
    float bsum[4];
#pragma unroll
    for (int j = 0; j < 4; ++j) {
        int g = g0 + tv * 4 + j;
        bsum[j] = b_ih[g] + b_hh[g];
    }
#pragma unroll
    for (int i = 0; i < 4; ++i) {
        int row = bs0 + tm * 4 + i;
        float4 o;
        o.x = acc[i][0] + bsum[0];
        o.y = acc[i][1] + bsum[1];
        o.z = acc[i][2] + bsum[2];
        o.w = acc[i][3] + bsum[3];
        *(float4*)(xp + (size_t)row * G4H + g0 + tv * 4) = o;
    }
}

// ---------------------------------------------------------------------------
// k2: persistent LSTM, tagged-word h exchange.
// 64 WGs x 512 thr: WG = chain (wg>>4) x slice (wg&15); slice owns 32 hidden
// units -> 128 gate rows; w_hh rows in registers (packed bf16).
// h(t) element e of chain c lives in hw[t&1][c][e] as (bf16(h)<<16 | tag),
// tag == t. Producer: ONE relaxed-agent 4B store (fire-and-forget).
// Consumer: polls the data word itself. One one-way MALL trip per step.
// ---------------------------------------------------------------------------
__global__ __launch_bounds__(512) void k_lstm(
    const float* __restrict__ w_hh, const float* __restrict__ xp,
    u32* __restrict__ hw, u16* __restrict__ hsaveB)
{
    __shared__ float hl[4 * 132];   // padded stride 132: quarters in distinct banks
    __shared__ float gacc[128];
    __shared__ float xs[128];

    const int tid   = threadIdx.x;
    const int wg    = blockIdx.x;
    const int c     = wg >> 4;        // chain 0..3
    const int slice = wg & 15;
    const int j0    = slice * 32;
    const int r     = tid >> 2;       // gate row in slice 0..127
    const int q     = tid & 3;        // k-quarter 0..3
    const int grow  = (r >> 5) * HID + j0 + (r & 31);

    // preload this thread's 128 w_hh values as packed bf16 (64 VGPRs)
    unsigned wreg[64];
    {
        const float* wsrc = w_hh + (size_t)grow * HID + q * 128;
#pragma unroll
        for (int i = 0; i < 32; ++i) {
            float4 f = *(const float4*)(wsrc + i * 4);
            wreg[2 * i]     = packbf(f.x, f.y);
            wreg[2 * i + 1] = packbf(f.z, f.w);
        }
    }

    float cst = 0.f;                  // cell state (tid<32)

    for (int t = 0; t < SS; ++t) {
        const int p = t & 1;
        // xp for this step (independent of h) - issue before poll
        if (tid < 128)
            xs[tid] = xp[(size_t)(c * SS + t) * G4H +
                         (tid >> 5) * HID + j0 + (tid & 31)];
        // poll tagged h word for element tid of this chain
        {
            u32* addr = hw + p * (BB * HID) + c * HID + tid;
            u32 w;
            int guard = 0;
            for (;;) {
                w = __hip_atomic_load(addr, __ATOMIC_RELAXED,
                                      __HIP_MEMORY_SCOPE_AGENT);
                if ((w & 0xffffu) == (u32)t) break;
                __builtin_amdgcn_s_sleep(1);
                if (++guard > 2000000) break;
            }
            hl[(tid >> 7) * 132 + (tid & 127)] = __uint_as_float(w & 0xffff0000u);
        }
        __syncthreads();

        // 128-element partial dot: row r, quarter q
        float acc = 0.f;
        {
            const float2* hq = (const float2*)(hl + q * 132);
#pragma unroll
            for (int kp = 0; kp < 64; ++kp) {
                unsigned w2 = wreg[kp];
                float2 h2 = hq[kp];
                acc = fmaf(h2.x, __uint_as_float(w2 << 16), acc);
                acc = fmaf(h2.y, __uint_as_float(w2 & 0xffff0000u), acc);
            }
        }
        // quad reduction (lanes q=0..3 of one row are adjacent)
        acc += __shfl_xor(acc, 1);
        acc += __shfl_xor(acc, 2);
        if (q == 0) gacc[r] = acc + xs[r];
        __syncthreads();

        if (tid < 32) {
            float iv = gacc[tid],      fv = gacc[32 + tid];
            float gv = gacc[64 + tid], ov = gacc[96 + tid];
            float si = 1.f / (1.f + __expf(-iv));
            float sf = 1.f / (1.f + __expf(-fv));
            float so = 1.f / (1.f + __expf(-ov));
            cst = sf * cst + si * tanhf(gv);
            float hv = so * tanhf(cst);
            unsigned u = __float_as_uint(hv);
            u += 0x7fffu + ((u >> 16) & 1u);
            u &= 0xffff0000u;                      // bf16 bits in hi16
            // tagged word for step t+1, fire-and-forget
            __hip_atomic_store(hw + (p ^ 1) * (BB * HID) + c * HID + j0 + tid,
                               u | (u32)(t + 1), __ATOMIC_RELAXED,
                               __HIP_MEMORY_SCOPE_AGENT);
            hsaveB[(size_t)(c * SS + t) * HID + j0 + tid] = (u16)(u >> 16);
        }
        // no trailing barrier needed: next-iter writes (xs, hl) only touch
        // locations whose readers passed the gacc barrier; gacc rewrite waits
        // at next-iter's post-poll barrier.
    }
}

// ---------------------------------------------------------------------------
// wcvt: W fp32 -> bf16 (RNE), 16.384M elems
// ---------------------------------------------------------------------------
__global__ __launch_bounds__(256) void k_wcvt(
    const float* __restrict__ W, u16* __restrict__ WB)
{
    int i = blockIdx.x * 256 + threadIdx.x;
    float4 f = ((const float4*)W)[i];
    uint2 o;
    o.x = packbf(f.x, f.y);
    o.y = packbf(f.z, f.w);
    ((uint2*)WB)[i] = o;
}

// ---------------------------------------------------------------------------
// k3: bf16 MFMA logits + fused exp/row-sum -> sumexp.
// 128x128 tile, BK=64, global_load_lds(16B) with chunk-XOR swizzle.
// ---------------------------------------------------------------------------
__global__ __launch_bounds__(256) void k_logits_lse(
    const u16* __restrict__ hsaveB, const u16* __restrict__ WB,
    const float* __restrict__ bias, float* __restrict__ sumexp)
{
    __shared__ u16 As[128 * 64];
    __shared__ u16 Bs[128 * 64];
    const int tid  = threadIdx.x;
    const int lane = tid & 63;
    const int wave = tid >> 6;
    const int wr   = wave >> 1;
    const int wc   = wave & 1;
    const int bs0  = blockIdx.x * 128;
    const int v0   = blockIdx.y * 128;
    const int lr   = lane & 15;
    const int lc   = lane >> 4;

    f32x4 acc[4][4];
#pragma unroll
    for (int m = 0; m < 4; ++m)
#pragma unroll
        for (int n = 0; n < 4; ++n)
            acc[m][n] = (f32x4){0.f, 0.f, 0.f, 0.f};

    for (int k0 = 0; k0 < HID; k0 += 64) {
#pragma unroll
        for (int it = 0; it < 4; ++it) {
            int base = it * 256 + wave * 64;
            int idx  = base + lane;
            int row  = idx >> 3, cl = idx & 7;
            int gcl  = cl ^ (row & 7);
            const u16* gA = hsaveB + (size_t)(bs0 + row) * HID + k0 + gcl * 8;
            GLOAD_LDS16(gA, As + (size_t)base * 8);
            const u16* gB = WB + (size_t)(v0 + row) * HID + k0 + gcl * 8;
            GLOAD_LDS16(gB, Bs + (size_t)base * 8);
        }
        asm volatile("s_waitcnt vmcnt(0)" ::: "memory");
        __syncthreads();

        short8 af[4][2], bf[4][2];
#pragma unroll
        for (int m = 0; m < 4; ++m)
#pragma unroll
            for (int ks = 0; ks < 2; ++ks) {
                int rowA = wr * 64 + m * 16 + lr;
                int swa  = ((ks * 4 + lc) ^ (rowA & 7)) * 8;
                af[m][ks] = *(const short8*)&As[rowA * 64 + swa];
                int rowB = wc * 64 + m * 16 + lr;
                int swb  = ((ks * 4 + lc) ^ (rowB & 7)) * 8;
                bf[m][ks] = *(const short8*)&Bs[rowB * 64 + swb];
            }
#pragma unroll
        for (int m = 0; m < 4; ++m)
#pragma unroll
            for (int n = 0; n < 4; ++n)
#pragma unroll
                for (int ks = 0; ks < 2; ++ks)
                    acc[m][n] = __builtin_amdgcn_mfma_f32_16x16x32_bf16(
                        af[m][ks], bf[n][ks], acc[m][n], 0, 0, 0);
        __syncthreads();
    }

    float bn[4];
#pragma unroll
    for (int n = 0; n < 4; ++n)
        bn[n] = bias[v0 + wc * 64 + n * 16 + lr];

#pragma unroll
    for (int m = 0; m < 4; ++m) {
        float p0 = 0.f, p1 = 0.f, p2 = 0.f, p3 = 0.f;
#pragma unroll
        for (int n = 0; n < 4; ++n) {
            float b = bn[n];
            p0 += __expf(acc[m][n][0] + b);
            p1 += __expf(acc[m][n][1] + b);
            p2 += __expf(acc[m][n][2] + b);
            p3 += __expf(acc[m][n][3] + b);
        }
#pragma unroll
        for (int off = 1; off < 16; off <<= 1) {
            p0 += __shfl_xor(p0, off);
            p1 += __shfl_xor(p1, off);
            p2 += __shfl_xor(p2, off);
            p3 += __shfl_xor(p3, off);
        }
        if (lr == 0) {
            int row = bs0 + wr * 64 + m * 16 + lc * 4;
            atomicAdd(&sumexp[row + 0], p0);
            atomicAdd(&sumexp[row + 1], p1);
            atomicAdd(&sumexp[row + 2], p2);
            atomicAdd(&sumexp[row + 3], p3);
        }
    }
}

// ---------------------------------------------------------------------------
// k4: one wave per (b,s): decode contiguous-view gather, recompute picked
// logit (bf16), subtract log(sumexp), accumulate -mean.
// ---------------------------------------------------------------------------
__device__ inline float dotp(u32 h, u32 w) {
    return __uint_as_float(h << 16) * __uint_as_float(w << 16) +
           __uint_as_float(h & 0xffff0000u) * __uint_as_float(w & 0xffff0000u);
}

__global__ __launch_bounds__(256) void k_final(
    const int* __restrict__ batch, const u16* __restrict__ hsaveB,
    const u16* __restrict__ WB, const float* __restrict__ bias,
    const float* __restrict__ sumexp, float* __restrict__ out)
{
    const int gt   = blockIdx.x * 256 + threadIdx.x;
    const int wid  = gt >> 6;
    const int lane = gt & 63;
    const unsigned tgt = (unsigned)batch[wid];
    const unsigned s2 = wid >> 2, b2 = wid & 3;
    const unsigned j = s2 * (VOCAB * BB) + tgt * BB + b2;
    const unsigned SV = (unsigned)SS * VOCAB;
    const unsigned b_o = j / SV;
    const unsigned rr = j - b_o * SV;
    const unsigned s_o = rr / VOCAB;
    const unsigned v_o = rr - s_o * VOCAB;
    const unsigned row = b_o * SS + s_o;

    uint4 hu = *(const uint4*)(hsaveB + (size_t)row * HID + lane * 8);
    uint4 wu = *(const uint4*)(WB + (size_t)v_o * HID + lane * 8);
    float d = dotp(hu.x, wu.x) + dotp(hu.y, wu.y) +
              dotp(hu.z, wu.z) + dotp(hu.w, wu.w);
#pragma unroll
    for (int off = 32; off >= 1; off >>= 1)
        d += __shfl_xor(d, off);
    if (lane == 0) {
        float picked = d + bias[v_o] - logf(sumexp[row]);
        atomicAdd(out, -picked * (1.f / (float)BS));
    }
}

// ---------------------------------------------------------------------------
extern "C" void kernel_launch(void* const* d_in, const int* in_sizes, int n_in,
                              void* d_out, int out_size, void* d_ws, size_t ws_size,
                              hipStream_t stream)
{
    const int*   batch = (const int*)d_in[0];
    const float* emb   = (const float*)d_in[1];
    const float* w_ih  = (const float*)d_in[2];
    const float* w_hh  = (const float*)d_in[3];
    const float* b_ih  = (const float*)d_in[4];
    const float* b_hh  = (const float*)d_in[5];
    const float* Wm    = (const float*)d_in[6];
    const float* bvec  = (const float*)d_in[7];
    float* out = (float*)d_out;
    float* ws  = (float*)d_ws;

    float* xp      = ws;                       // dead after k2
    u16*   WB      = (u16*)ws;                 // written after k2 (time-shared)
    u16*   hsaveB  = (u16*)(ws + OFF_HSB);
    u32*   hw      = (u32*)(ws + OFF_HW);
    float* sumexp  = ws + OFF_SUM;

    // zero hw + (unused flag region) + sumexp (contiguous) and out
    hipMemsetAsync(hw, 0, (4096 + 2048 + 2048) * sizeof(float), stream);
    hipMemsetAsync(out, 0, sizeof(float), stream);

    dim3 g1(BS / 64, G4H / 64);
    k_embed_xp<<<g1, 256, 0, stream>>>(batch, emb, w_ih, b_ih, b_hh, xp);

    k_lstm<<<64, 512, 0, stream>>>(w_hh, xp, hw, hsaveB);

    k_wcvt<<<VOCAB * HID / 4 / 256, 256, 0, stream>>>(Wm, WB);

    dim3 g3(BS / 128, VOCAB / 128);
    k_logits_lse<<<g3, 256, 0, stream>>>(hsaveB, WB, bvec, sumexp);

    k_final<<<BS * 64 / 256, 256, 0, stream>>>(batch, hsaveB, WB, bvec, sumexp, out);
}